// Round 5
// baseline (495.675 us; speedup 1.0000x reference)
//
#include <hip/hip_runtime.h>

#define N_NODES 100000
#define N_EDGES 500000
#define H 128
#define EPS 1e-5f
#define NT_E 1954   // ceil(500000/256)
#define NT_N 391    // ceil(100000/256)
#define PGRID 256

typedef __attribute__((ext_vector_type(8))) short bf16x8;
typedef __attribute__((ext_vector_type(4))) float f32x4;

__device__ __forceinline__ unsigned short f2bf(float f) {
  unsigned int u = __builtin_bit_cast(unsigned int, f);
  u += 0x7FFFu + ((u >> 16) & 1u);
  return (unsigned short)(u >> 16);
}
__device__ __forceinline__ float bf2f(unsigned short u) {
  return __builtin_bit_cast(float, (unsigned)u << 16);
}

// XOR-swizzled LDS layout for [R x 128] bf16 tiles.
// (r,k) -> ushort idx r*128 + (k ^ ((r&7)<<3)); 16B chunks stay intact.
__device__ __forceinline__ int swz(int r, int k) {
  return r * 128 + (k ^ ((r & 7) << 3));
}

union PK8 { unsigned short u[8]; uint4 q; };

#define GLDS16(g, l)                                                        \
  __builtin_amdgcn_global_load_lds(                                         \
      (const __attribute__((address_space(1))) void*)(g),                   \
      (__attribute__((address_space(3))) void*)(l), 16, 0, 0)

// acc[8] += A(regs)[16 x 128] @ W(LDS)[128 -> 128]
__device__ __forceinline__ void gemm_regA(const bf16x8 a[4], const unsigned short* Wb,
                                          int m0, int kq, f32x4 acc[8]) {
  #pragma unroll
  for (int kk = 0; kk < 4; ++kk) {
    const int k0 = kk * 32 + kq * 8;
    #pragma unroll
    for (int tc = 0; tc < 8; ++tc) {
      bf16x8 b = *(const bf16x8*)&Wb[swz(tc * 16 + m0, k0)];
      acc[tc] = __builtin_amdgcn_mfma_f32_16x16x32_bf16(a[kk], b, acc[tc], 0, 0, 0);
    }
  }
}

// acc[8] += A(LDS rows wrow..wrow+16) @ W(LDS)
__device__ __forceinline__ void gemm_ldsA(const unsigned short* Hb, int wrow,
                                          const unsigned short* Wb,
                                          int m0, int kq, f32x4 acc[8]) {
  #pragma unroll
  for (int kk = 0; kk < 4; ++kk) {
    const int k0 = kk * 32 + kq * 8;
    bf16x8 a = *(const bf16x8*)&Hb[swz(wrow + m0, k0)];
    #pragma unroll
    for (int tc = 0; tc < 8; ++tc) {
      bf16x8 b = *(const bf16x8*)&Wb[swz(tc * 16 + m0, k0)];
      acc[tc] = __builtin_amdgcn_mfma_f32_16x16x32_bf16(a, b, acc[tc], 0, 0, 0);
    }
  }
}

__device__ __forceinline__ void zero_acc(f32x4 acc[8]) {
  #pragma unroll
  for (int b = 0; b < 8; ++b) acc[b] = (f32x4){0.f, 0.f, 0.f, 0.f};
}

__device__ __forceinline__ void ln4(const f32x4 acc[8], float mu[4], float rv[4]) {
  float s[4] = {0, 0, 0, 0}, ss[4] = {0, 0, 0, 0};
  #pragma unroll
  for (int tc = 0; tc < 8; ++tc)
    #pragma unroll
    for (int i = 0; i < 4; ++i) {
      const float v = acc[tc][i];
      s[i] += v;
      ss[i] += v * v;
    }
  #pragma unroll
  for (int off = 1; off < 16; off <<= 1)
    #pragma unroll
    for (int i = 0; i < 4; ++i) {
      s[i] += __shfl_xor(s[i], off);
      ss[i] += __shfl_xor(ss[i], off);
    }
  #pragma unroll
  for (int i = 0; i < 4; ++i) {
    const float m = s[i] * (1.0f / 128.0f);
    const float var = ss[i] * (1.0f / 128.0f) - m * m;
    mu[i] = m;
    rv[i] = rsqrtf(var + EPS);
  }
}

// ---------------- weight images ----------------

struct WSrc { const float* p[9]; };

// Pre-swizzled LDS image: wimg[m*16384 + swz(n,k)] = W_m[k][n] (bf16)
__global__ void wprep_kernel(WSrc wsrc, unsigned short* __restrict__ wimg) {
  const int id = blockIdx.x * 256 + threadIdx.x;  // 9*16384
  const int m = id >> 14;
  const int r = id & 16383;
  const int n = r & 127;
  const int k = r >> 7;
  wimg[m * 16384 + swz(n, k)] = f2bf(wsrc.p[m][k * 128 + n]);
}

// ---------------- px precompute: px_s = x@eW1a+eb1, px_r = x@eW1b, px_n = x@nW1a+nb1
// stored PERMUTED: px[node][m0*8+tc] = value for feature col tc*16+m0.

__global__ __launch_bounds__(512, 2) void px_kernel(
    const float* __restrict__ x, const unsigned short* __restrict__ wimg,
    const float* __restrict__ eb1, const float* __restrict__ nb1,
    unsigned short* __restrict__ pxs, unsigned short* __restrict__ pxr,
    unsigned short* __restrict__ pxn) {
  extern __shared__ unsigned short smem[];  // 3 * 16384 (96KB)
  const int t = threadIdx.x;
  #pragma unroll
  for (int j = 0; j < 12; ++j)
    GLDS16((const char*)wimg + j * 8192 + t * 16, (char*)smem + j * 8192 + t * 16);
  __syncthreads();

  const int lane = t & 63;
  const int wtile = (t >> 6) * 16;
  const int m0 = lane & 15;
  const int kq = lane >> 4;
  const long n0 = (long)blockIdx.x * 128;

  long an = n0 + wtile + m0;
  if (an > N_NODES - 1) an = N_NODES - 1;
  const float* px_ = x + an * H + kq * 8;
  bf16x8 aX[4];
  #pragma unroll
  for (int kk = 0; kk < 4; ++kk) {
    float4 v0 = *(const float4*)(px_ + kk * 32);
    float4 v1 = *(const float4*)(px_ + kk * 32 + 4);
    PK8 pk;
    pk.u[0] = f2bf(v0.x); pk.u[1] = f2bf(v0.y);
    pk.u[2] = f2bf(v0.z); pk.u[3] = f2bf(v0.w);
    pk.u[4] = f2bf(v1.x); pk.u[5] = f2bf(v1.y);
    pk.u[6] = f2bf(v1.z); pk.u[7] = f2bf(v1.w);
    aX[kk] = __builtin_bit_cast(bf16x8, pk.q);
  }
  const long cb = n0 + wtile + kq * 4;

  f32x4 acc[8];
  float bv[8];
  // px_s
  zero_acc(acc);
  gemm_regA(aX, smem, m0, kq, acc);
  #pragma unroll
  for (int tc = 0; tc < 8; ++tc) bv[tc] = eb1[tc * 16 + m0];
  #pragma unroll
  for (int i = 0; i < 4; ++i) {
    const long nn = cb + i;
    if (nn < N_NODES) {
      PK8 pk;
      #pragma unroll
      for (int tc = 0; tc < 8; ++tc) pk.u[tc] = f2bf(acc[tc][i] + bv[tc]);
      *(uint4*)(pxs + nn * H + m0 * 8) = pk.q;
    }
  }
  // px_r
  zero_acc(acc);
  gemm_regA(aX, smem + 16384, m0, kq, acc);
  #pragma unroll
  for (int i = 0; i < 4; ++i) {
    const long nn = cb + i;
    if (nn < N_NODES) {
      PK8 pk;
      #pragma unroll
      for (int tc = 0; tc < 8; ++tc) pk.u[tc] = f2bf(acc[tc][i]);
      *(uint4*)(pxr + nn * H + m0 * 8) = pk.q;
    }
  }
  // px_n
  zero_acc(acc);
  gemm_regA(aX, smem + 32768, m0, kq, acc);
  #pragma unroll
  for (int tc = 0; tc < 8; ++tc) bv[tc] = nb1[tc * 16 + m0];
  #pragma unroll
  for (int i = 0; i < 4; ++i) {
    const long nn = cb + i;
    if (nn < N_NODES) {
      PK8 pk;
      #pragma unroll
      for (int tc = 0; tc < 8; ++tc) pk.u[tc] = f2bf(acc[tc][i] + bv[tc]);
      *(uint4*)(pxn + nn * H + m0 * 8) = pk.q;
    }
  }
}

// ---------------- CSR build ----------------

__global__ void hist_kernel(const int* __restrict__ ridx, unsigned* __restrict__ cnt) {
  const int e = blockIdx.x * 256 + threadIdx.x;
  if (e < N_EDGES) atomicAdd(&cnt[ridx[e]], 1u);
}

__global__ void scan1_kernel(const unsigned* __restrict__ cnt,
                             unsigned* __restrict__ offs,
                             unsigned* __restrict__ part) {
  __shared__ unsigned sh[256];
  const int t = threadIdx.x;
  const int base = blockIdx.x * 1024 + t * 4;
  unsigned v[4];
  #pragma unroll
  for (int i = 0; i < 4; ++i) v[i] = (base + i < N_NODES) ? cnt[base + i] : 0u;
  unsigned pre[4];
  pre[0] = 0; pre[1] = v[0]; pre[2] = v[0] + v[1]; pre[3] = pre[2] + v[2];
  const unsigned tot = pre[3] + v[3];
  sh[t] = tot;
  __syncthreads();
  for (int d = 1; d < 256; d <<= 1) {
    const unsigned u_ = (t >= d) ? sh[t - d] : 0u;
    __syncthreads();
    sh[t] += u_;
    __syncthreads();
  }
  const unsigned excl = sh[t] - tot;
  #pragma unroll
  for (int i = 0; i < 4; ++i)
    if (base + i < N_NODES) offs[base + i] = excl + pre[i];
  if (t == 255) part[blockIdx.x] = sh[255];
}

__global__ void scan2_kernel(unsigned* __restrict__ part, int n) {
  __shared__ unsigned sh[128];
  const int t = threadIdx.x;
  const unsigned v = (t < n) ? part[t] : 0u;
  sh[t] = v;
  __syncthreads();
  for (int d = 1; d < 128; d <<= 1) {
    const unsigned u_ = (t >= d) ? sh[t - d] : 0u;
    __syncthreads();
    sh[t] += u_;
    __syncthreads();
  }
  if (t < n) part[t] = sh[t] - v;
}

__global__ void scan3_kernel(unsigned* __restrict__ offs,
                             const unsigned* __restrict__ part,
                             unsigned* __restrict__ cursor) {
  const int i = blockIdx.x * 256 + threadIdx.x;
  if (i < N_NODES) {
    const unsigned o = offs[i] + part[i >> 10];
    offs[i] = o;
    cursor[i] = o;
  }
  if (i == 0) offs[N_NODES] = N_EDGES;
}

__global__ void scatter_kernel(const int* __restrict__ ridx,
                               unsigned* __restrict__ cursor,
                               int* __restrict__ slot) {
  const int e = blockIdx.x * 256 + threadIdx.x;
  if (e < N_EDGES) slot[e] = (int)atomicAdd(&cursor[ridx[e]], 1u);
}

// ---------------- main kernels ----------------
// Persistent blocks; weights resident in LDS; h1/h2 handoffs are wave-local
// (each wave owns rows [wtile, wtile+16) of Hb) => NO barriers in the tile loop.

__global__ __launch_bounds__(1024, 4) void edge_kernel(
    const float* __restrict__ edge_attr, const int* __restrict__ eidx,
    const int* __restrict__ slot, const unsigned short* __restrict__ wimg,
    const unsigned short* __restrict__ pxs, const unsigned short* __restrict__ pxr,
    const float* __restrict__ eb2, const float* __restrict__ eb3,
    const float* __restrict__ eg, const float* __restrict__ ebeta,
    float* __restrict__ out_e, unsigned short* __restrict__ enew) {
  extern __shared__ unsigned short smem[];  // W1c|W2|W3 (96KB) + Hb (64KB)
  unsigned short* Wc = smem;
  unsigned short* W2 = smem + 16384;
  unsigned short* W3 = smem + 32768;
  unsigned short* Hb = smem + 49152;
  const int t = threadIdx.x;
  #pragma unroll
  for (int j = 0; j < 6; ++j)
    GLDS16((const char*)(wimg + 3 * 16384) + j * 16384 + t * 16,
           (char*)smem + j * 16384 + t * 16);
  __syncthreads();

  const int lane = t & 63;
  const int wtile = (t >> 6) * 16;
  const int m0 = lane & 15;
  const int kq = lane >> 4;
  const int* sidx = eidx;
  const int* ridx = eidx + N_EDGES;

  for (int tile = blockIdx.x; tile < NT_E; tile += PGRID) {
    const long e0 = (long)tile * 256;
    const long cb = e0 + wtile + kq * 4;
    const long cbl = cb > (long)(N_EDGES - 4) ? (long)(N_EDGES - 4) : cb;
    int4 s4 = *(const int4*)&sidx[cbl];
    int4 r4 = *(const int4*)&ridx[cbl];
    int4 p4 = *(const int4*)&slot[cbl];
    const int* sp = (const int*)&s4;
    const int* rp = (const int*)&r4;
    const int* pp = (const int*)&p4;

    long ae = e0 + wtile + m0;
    if (ae > N_EDGES - 1) ae = N_EDGES - 1;
    const float* pe = edge_attr + ae * H + kq * 8;
    bf16x8 aE[4];
    #pragma unroll
    for (int kk = 0; kk < 4; ++kk) {
      float4 v0 = *(const float4*)(pe + kk * 32);
      float4 v1 = *(const float4*)(pe + kk * 32 + 4);
      PK8 pk;
      pk.u[0] = f2bf(v0.x); pk.u[1] = f2bf(v0.y);
      pk.u[2] = f2bf(v0.z); pk.u[3] = f2bf(v0.w);
      pk.u[4] = f2bf(v1.x); pk.u[5] = f2bf(v1.y);
      pk.u[6] = f2bf(v1.z); pk.u[7] = f2bf(v1.w);
      aE[kk] = __builtin_bit_cast(bf16x8, pk.q);
    }
    uint4 qs[4], qr[4];
    #pragma unroll
    for (int i = 0; i < 4; ++i) {
      qs[i] = *(const uint4*)(pxs + (long)sp[i] * H + m0 * 8);
      qr[i] = *(const uint4*)(pxr + (long)rp[i] * H + m0 * 8);
    }

    f32x4 acc[8];
    zero_acc(acc);
    gemm_regA(aE, Wc, m0, kq, acc);
    #pragma unroll
    for (int i = 0; i < 4; ++i) {
      const unsigned short* us = (const unsigned short*)&qs[i];
      const unsigned short* ur = (const unsigned short*)&qr[i];
      #pragma unroll
      for (int tc = 0; tc < 8; ++tc)
        acc[tc][i] += bf2f(us[tc]) + bf2f(ur[tc]);
    }
    // h1 (bias already folded into pxs) -> wave-local Hb rows
    #pragma unroll
    for (int tc = 0; tc < 8; ++tc) {
      const int col = tc * 16 + m0;
      #pragma unroll
      for (int i = 0; i < 4; ++i)
        Hb[swz(wtile + kq * 4 + i, col)] = f2bf(fmaxf(acc[tc][i], 0.f));
    }
    zero_acc(acc);
    gemm_ldsA(Hb, wtile, W2, m0, kq, acc);
    float b2v[8];
    #pragma unroll
    for (int tc = 0; tc < 8; ++tc) b2v[tc] = eb2[tc * 16 + m0];
    #pragma unroll
    for (int tc = 0; tc < 8; ++tc) {
      const int col = tc * 16 + m0;
      #pragma unroll
      for (int i = 0; i < 4; ++i)
        Hb[swz(wtile + kq * 4 + i, col)] = f2bf(fmaxf(acc[tc][i] + b2v[tc], 0.f));
    }
    zero_acc(acc);
    gemm_ldsA(Hb, wtile, W3, m0, kq, acc);

    float b3v[8], gv[8], btv[8];
    #pragma unroll
    for (int tc = 0; tc < 8; ++tc) {
      const int col = tc * 16 + m0;
      b3v[tc] = eb3[col];
      gv[tc] = eg[col];
      btv[tc] = ebeta[col];
    }
    #pragma unroll
    for (int tc = 0; tc < 8; ++tc)
      #pragma unroll
      for (int i = 0; i < 4; ++i) acc[tc][i] += b3v[tc];
    float mu[4], rv[4];
    ln4(acc, mu, rv);

    #pragma unroll
    for (int i = 0; i < 4; ++i) {
      const long er = cb + i;
      if (er < N_EDGES) {
        const long ps = (long)pp[i] * H;
        #pragma unroll
        for (int tc = 0; tc < 8; ++tc) {
          const int col = tc * 16 + m0;
          const float y = (acc[tc][i] - mu[i]) * rv[i] * gv[tc] + btv[tc];
          out_e[er * H + col] = edge_attr[er * H + col] + y;
          enew[ps + col] = f2bf(y);
        }
      }
    }
  }
}

__global__ __launch_bounds__(1024, 4) void node_kernel(
    const float* __restrict__ x, const unsigned short* __restrict__ enew,
    const unsigned* __restrict__ offs, const unsigned short* __restrict__ wimg,
    const unsigned short* __restrict__ pxn,
    const float* __restrict__ nb2, const float* __restrict__ nb3,
    const float* __restrict__ ng, const float* __restrict__ nbeta,
    float* __restrict__ out_x) {
  extern __shared__ unsigned short smem[];  // nW1b|nW2|nW3 (96KB) + Hb (64KB)
  unsigned short* W1 = smem;
  unsigned short* W2 = smem + 16384;
  unsigned short* W3 = smem + 32768;
  unsigned short* Hb = smem + 49152;
  const int t = threadIdx.x;
  #pragma unroll
  for (int j = 0; j < 6; ++j)
    GLDS16((const char*)(wimg + 6 * 16384) + j * 16384 + t * 16,
           (char*)smem + j * 16384 + t * 16);
  __syncthreads();

  const int lane = t & 63;
  const int wtile = (t >> 6) * 16;
  const int m0 = lane & 15;
  const int kq = lane >> 4;

  for (int tile = blockIdx.x; tile < NT_N; tile += PGRID) {
    const long n0 = (long)tile * 256;
    long an = n0 + wtile + m0;
    if (an > N_NODES - 1) an = N_NODES - 1;
    const unsigned o0 = offs[an], o1 = offs[an + 1];

    // agg A-fragments: CSR rows are contiguous in enew (CSR-ordered store)
    float sm[4][8];
    #pragma unroll
    for (int kk = 0; kk < 4; ++kk)
      #pragma unroll
      for (int c = 0; c < 8; ++c) sm[kk][c] = 0.f;
    for (unsigned j = o0; j < o1; ++j) {
      const unsigned short* er = enew + (long)j * H + kq * 8;
      #pragma unroll
      for (int kk = 0; kk < 4; ++kk) {
        uint4 q = *(const uint4*)(er + kk * 32);
        const unsigned short* pu = (const unsigned short*)&q;
        #pragma unroll
        for (int c = 0; c < 8; ++c) sm[kk][c] += bf2f(pu[c]);
      }
    }
    bf16x8 aG[4];
    #pragma unroll
    for (int kk = 0; kk < 4; ++kk) {
      PK8 pk;
      #pragma unroll
      for (int c = 0; c < 8; ++c) pk.u[c] = f2bf(sm[kk][c]);
      aG[kk] = __builtin_bit_cast(bf16x8, pk.q);
    }

    const long cb = n0 + wtile + kq * 4;
    const long cbl = cb > (long)(N_NODES - 4) ? (long)(N_NODES - 4) : cb;
    uint4 qn[4];
    #pragma unroll
    for (int i = 0; i < 4; ++i)
      qn[i] = *(const uint4*)(pxn + (cbl + i) * H + m0 * 8);

    f32x4 acc[8];
    zero_acc(acc);
    gemm_regA(aG, W1, m0, kq, acc);
    #pragma unroll
    for (int i = 0; i < 4; ++i) {
      const unsigned short* un = (const unsigned short*)&qn[i];
      #pragma unroll
      for (int tc = 0; tc < 8; ++tc) acc[tc][i] += bf2f(un[tc]);
    }
    #pragma unroll
    for (int tc = 0; tc < 8; ++tc) {
      const int col = tc * 16 + m0;
      #pragma unroll
      for (int i = 0; i < 4; ++i)
        Hb[swz(wtile + kq * 4 + i, col)] = f2bf(fmaxf(acc[tc][i], 0.f));
    }
    zero_acc(acc);
    gemm_ldsA(Hb, wtile, W2, m0, kq, acc);
    float b2v[8];
    #pragma unroll
    for (int tc = 0; tc < 8; ++tc) b2v[tc] = nb2[tc * 16 + m0];
    #pragma unroll
    for (int tc = 0; tc < 8; ++tc) {
      const int col = tc * 16 + m0;
      #pragma unroll
      for (int i = 0; i < 4; ++i)
        Hb[swz(wtile + kq * 4 + i, col)] = f2bf(fmaxf(acc[tc][i] + b2v[tc], 0.f));
    }
    zero_acc(acc);
    gemm_ldsA(Hb, wtile, W3, m0, kq, acc);

    float b3v[8], gv[8], btv[8];
    #pragma unroll
    for (int tc = 0; tc < 8; ++tc) {
      const int col = tc * 16 + m0;
      b3v[tc] = nb3[col];
      gv[tc] = ng[col];
      btv[tc] = nbeta[col];
    }
    #pragma unroll
    for (int tc = 0; tc < 8; ++tc)
      #pragma unroll
      for (int i = 0; i < 4; ++i) acc[tc][i] += b3v[tc];
    float mu[4], rv[4];
    ln4(acc, mu, rv);

    #pragma unroll
    for (int i = 0; i < 4; ++i) {
      const long nn = cb + i;
      if (nn < N_NODES) {
        #pragma unroll
        for (int tc = 0; tc < 8; ++tc) {
          const int col = tc * 16 + m0;
          const float y = (acc[tc][i] - mu[i]) * rv[i] * gv[tc] + btv[tc];
          out_x[nn * H + col] = x[nn * H + col] + y;
        }
      }
    }
  }
}

extern "C" void kernel_launch(void* const* d_in, const int* in_sizes, int n_in,
                              void* d_out, int out_size, void* d_ws, size_t ws_size,
                              hipStream_t stream) {
  (void)in_sizes; (void)n_in; (void)out_size; (void)ws_size;
  const float* x         = (const float*)d_in[0];
  const float* edge_attr = (const float*)d_in[1];
  const int*   eidx      = (const int*)d_in[2];
  const float* eW1 = (const float*)d_in[3];
  const float* eb1 = (const float*)d_in[4];
  const float* eW2 = (const float*)d_in[5];
  const float* eb2 = (const float*)d_in[6];
  const float* eW3 = (const float*)d_in[7];
  const float* eb3 = (const float*)d_in[8];
  const float* eg  = (const float*)d_in[9];
  const float* ebt = (const float*)d_in[10];
  const float* nW1 = (const float*)d_in[11];
  const float* nb1 = (const float*)d_in[12];
  const float* nW2 = (const float*)d_in[13];
  const float* nb2 = (const float*)d_in[14];
  const float* nW3 = (const float*)d_in[15];
  const float* nb3 = (const float*)d_in[16];
  const float* ng  = (const float*)d_in[17];
  const float* nbt = (const float*)d_in[18];

  float* out_x = (float*)d_out;                        // N_NODES*H
  float* out_e = (float*)d_out + (size_t)N_NODES * H;  // N_EDGES*H

  // ws layout (bytes)
  char* w = (char*)d_ws;
  unsigned short* enew = (unsigned short*)(w + 0);            // 128,000,000
  unsigned short* pxs  = (unsigned short*)(w + 128000000);    //  25,600,000
  unsigned short* pxr  = (unsigned short*)(w + 153600000);    //  25,600,000
  unsigned short* pxn  = (unsigned short*)(w + 179200000);    //  25,600,000
  unsigned short* wimg = (unsigned short*)(w + 204800000);    //     294,912
  unsigned* offs   = (unsigned*)(w + 205094912);              //     400,128
  unsigned* cnt    = (unsigned*)(w + 205495040);              //     400,128
  unsigned* cursor = (unsigned*)(w + 205895168);              //     400,128
  unsigned* part   = (unsigned*)(w + 206295296);              //       1,024
  int* slot        = (int*)(w + 206296320);                   //   2,000,000
  // total ~208.3 MB

  const int* ridx = eidx + N_EDGES;

  hipFuncSetAttribute((const void*)px_kernel,
                      hipFuncAttributeMaxDynamicSharedMemorySize, 98304);
  hipFuncSetAttribute((const void*)edge_kernel,
                      hipFuncAttributeMaxDynamicSharedMemorySize, 163840);
  hipFuncSetAttribute((const void*)node_kernel,
                      hipFuncAttributeMaxDynamicSharedMemorySize, 163840);

  hipMemsetAsync(cnt, 0, (size_t)N_NODES * sizeof(unsigned), stream);

  WSrc wsrc;
  wsrc.p[0] = eW1;                 // eW1a (senders)
  wsrc.p[1] = eW1 + 16384;         // eW1b (receivers)
  wsrc.p[2] = nW1;                 // nW1a (x)
  wsrc.p[3] = eW1 + 32768;         // eW1c (edge_attr)
  wsrc.p[4] = eW2;
  wsrc.p[5] = eW3;
  wsrc.p[6] = nW1 + 16384;         // nW1b (agg)
  wsrc.p[7] = nW2;
  wsrc.p[8] = nW3;
  wprep_kernel<<<576, 256, 0, stream>>>(wsrc, wimg);

  px_kernel<<<(N_NODES + 127) / 128, 512, 98304, stream>>>(x, wimg, eb1, nb1,
                                                           pxs, pxr, pxn);

  hist_kernel<<<(N_EDGES + 255) / 256, 256, 0, stream>>>(ridx, cnt);
  scan1_kernel<<<(N_NODES + 1023) / 1024, 256, 0, stream>>>(cnt, offs, part);
  scan2_kernel<<<1, 128, 0, stream>>>(part, (N_NODES + 1023) / 1024);
  scan3_kernel<<<(N_NODES + 255) / 256, 256, 0, stream>>>(offs, part, cursor);
  scatter_kernel<<<(N_EDGES + 255) / 256, 256, 0, stream>>>(ridx, cursor, slot);

  edge_kernel<<<PGRID, 1024, 163840, stream>>>(edge_attr, eidx, slot, wimg,
                                               pxs, pxr, eb2, eb3, eg, ebt,
                                               out_e, enew);
  node_kernel<<<PGRID, 1024, 163840, stream>>>(x, enew, offs, wimg, pxn,
                                               nb2, nb3, ng, nbt, out_x);
}